// Round 1
// baseline (3939.272 us; speedup 1.0000x reference)
//
#include <hip/hip_runtime.h>
#include <math.h>

// Problem constants (from reference): F_IN=64, K=16, C=20, L=4, H1=20, H2=2

// ---------------- Kernel A: both filter nets for 1.6M unique edge attrs ---------
// attr2 = [attr; attr], so each undirected edge's filter weight is computed once
// and reused for both directions.
__global__ __launch_bounds__(256) void filter_kernel(
    const float* __restrict__ attr, const float* __restrict__ cutoffs,
    const float* __restrict__ cw1, const float* __restrict__ cb1,
    const float* __restrict__ f1w1, const float* __restrict__ f1b1,
    const float* __restrict__ f2w1, const float* __restrict__ f2b1,
    const float* __restrict__ cw2, const float* __restrict__ cb2,
    const float* __restrict__ f1w2, const float* __restrict__ f1b2,
    const float* __restrict__ f2w2, const float* __restrict__ f2b2,
    float* __restrict__ wedge1, float* __restrict__ wedge2, int E)
{
    __shared__ float s_cut[16];
    __shared__ float s_w[2][344]; // cw(120) cb(20) f1w(160) f1b(8) f2w(32) f2b(4)
    int tid = threadIdx.x;
    if (tid < 16) s_cut[tid] = cutoffs[tid];
    for (int i = tid; i < 344; i += 256) {
        float v1, v2;
        if (i < 120)      { v1 = cw1[i];       v2 = cw2[i]; }
        else if (i < 140) { v1 = cb1[i-120];   v2 = cb2[i-120]; }
        else if (i < 300) { v1 = f1w1[i-140];  v2 = f1w2[i-140]; }
        else if (i < 308) { v1 = f1b1[i-300];  v2 = f1b2[i-300]; }
        else if (i < 340) { v1 = f2w1[i-308];  v2 = f2w2[i-308]; }
        else              { v1 = f2b1[i-340];  v2 = f2b2[i-340]; }
        s_w[0][i] = v1; s_w[1][i] = v2;
    }
    __syncthreads();
    int e = blockIdx.x * 256 + tid;
    if (e >= E) return;
    float a = attr[e];
    // padded conv input: dp[0]=dp[17]=0 (zero padding), dp[k+1] = a - cut[k]
    float dp[18], sp[18];
    dp[0] = 0.f; sp[0] = 0.f; dp[17] = 0.f; sp[17] = 0.f;
    #pragma unroll
    for (int k = 0; k < 16; ++k) {
        float d = a - s_cut[k];
        dp[k+1] = d;
        sp[k+1] = d > 0.f ? 1.f : 0.f;
    }
    #pragma unroll
    for (int layer = 0; layer < 2; ++layer) {
        const float* W = s_w[layer];
        float h[20];
        #pragma unroll
        for (int c = 0; c < 20; ++c) {
            float w00 = W[c*6+0], w01 = W[c*6+1], w02 = W[c*6+2];
            float w10 = W[c*6+3], w11 = W[c*6+4], w12 = W[c*6+5];
            float b = W[120 + c];
            float m = -1e30f;
            #pragma unroll
            for (int k = 0; k < 16; ++k) {
                // y[k] = b + sum_t sig[0][k+t-1]*w0t + sig[1][k+t-1]*w1t
                float v = b + dp[k]*w00 + dp[k+1]*w01 + dp[k+2]*w02
                            + sp[k]*w10 + sp[k+1]*w11 + sp[k+2]*w12;
                m = fmaxf(m, v);
            }
            h[c] = fmaxf(m, 0.f);   // relu(max_k)
        }
        float g[8];
        #pragma unroll
        for (int j = 0; j < 8; ++j) {
            float t = W[300 + j];
            #pragma unroll
            for (int c = 0; c < 20; ++c) t += W[140 + j*20 + c] * h[c];
            g[j] = fmaxf(t, 0.f);
        }
        float4 wo;
        float* wp = (float*)&wo;
        #pragma unroll
        for (int l = 0; l < 4; ++l) {
            float t = W[340 + l];
            #pragma unroll
            for (int j = 0; j < 8; ++j) t += W[308 + l*8 + j] * g[j];
            wp[l] = fmaxf(t, 0.f);
        }
        float4* dstp = (float4*)(layer == 0 ? wedge1 : wedge2);
        dstp[e] = wo;
    }
}

// ---------------- Kernel B: h1 = x@root1 + bias1 ; P1[n,l,h] = x[n]@theta1[l] ----
__global__ __launch_bounds__(256) void node_prep1(
    const float* __restrict__ x, const float* __restrict__ root1,
    const float* __restrict__ theta1, const float* __restrict__ bias1,
    float* __restrict__ h1, float* __restrict__ P1, int N)
{
    __shared__ float Ws[64 * 100];  // cols 0..19 root1, 20..99 theta1[l][.,h]
    __shared__ float xs[8 * 64];
    __shared__ float sb[20];
    int tid = threadIdx.x;
    for (int i = tid; i < 6400; i += 256) {
        int f = i / 100, c = i % 100;
        float v;
        if (c < 20) v = root1[f*20 + c];
        else { int l = (c-20)/20, hh = (c-20)%20; v = theta1[l*1280 + f*20 + hh]; }
        Ws[i] = v;
    }
    if (tid < 20) sb[tid] = bias1[tid];
    int nb = blockIdx.x * 8;
    for (int i = tid; i < 512; i += 256) {
        int nl = i >> 6, f = i & 63;
        int n = nb + nl;
        xs[i] = (n < N) ? x[(size_t)n*64 + f] : 0.f;
    }
    __syncthreads();
    for (int i = tid; i < 800; i += 256) {
        int nl = i / 100, c = i % 100;
        int n = nb + nl;
        if (n >= N) continue;
        float acc = 0.f;
        #pragma unroll 16
        for (int f = 0; f < 64; ++f) acc += xs[nl*64 + f] * Ws[f*100 + c];
        if (c < 20) h1[(size_t)n*20 + c] = acc + sb[c];
        else        P1[(size_t)n*80 + (c - 20)] = acc;
    }
}

// ---------------- Kernel C: edge scatter layer 1 --------------------------------
// y[h] = sum_l w_l * P1[src][l][h]  -> atomicAdd into h1[dst][h]; and mirrored.
__global__ __launch_bounds__(256) void edge_scatter1(
    const int* __restrict__ ei, const float4* __restrict__ wedge1,
    const float4* __restrict__ P1, float* __restrict__ h1, int E)
{
    int e = blockIdx.x * 256 + threadIdx.x;
    if (e >= E) return;
    int s = ei[e], d = ei[E + e];
    float4 w = wedge1[e];
    const float4* Ps = P1 + (size_t)s * 20;
    const float4* Pd = P1 + (size_t)d * 20;
    float* Hs = h1 + (size_t)s * 20;
    float* Hd = h1 + (size_t)d * 20;
    #pragma unroll
    for (int q = 0; q < 5; ++q) {
        float4 a0 = Ps[q], a1 = Ps[5+q], a2 = Ps[10+q], a3 = Ps[15+q];
        atomicAdd(Hd + q*4 + 0, w.x*a0.x + w.y*a1.x + w.z*a2.x + w.w*a3.x);
        atomicAdd(Hd + q*4 + 1, w.x*a0.y + w.y*a1.y + w.z*a2.y + w.w*a3.y);
        atomicAdd(Hd + q*4 + 2, w.x*a0.z + w.y*a1.z + w.z*a2.z + w.w*a3.z);
        atomicAdd(Hd + q*4 + 3, w.x*a0.w + w.y*a1.w + w.z*a2.w + w.w*a3.w);
        float4 b0 = Pd[q], b1 = Pd[5+q], b2 = Pd[10+q], b3 = Pd[15+q];
        atomicAdd(Hs + q*4 + 0, w.x*b0.x + w.y*b1.x + w.z*b2.x + w.w*b3.x);
        atomicAdd(Hs + q*4 + 1, w.x*b0.y + w.y*b1.y + w.z*b2.y + w.w*b3.y);
        atomicAdd(Hs + q*4 + 2, w.x*b0.z + w.y*b1.z + w.z*b2.z + w.w*b3.z);
        atomicAdd(Hs + q*4 + 3, w.x*b0.w + w.y*b1.w + w.z*b2.w + w.w*b3.w);
    }
}

// ---------------- Kernel D: relu(h1); out2 = r@root2+bias2; P2[n,l,j] -----------
__global__ __launch_bounds__(256) void node_prep2(
    const float* __restrict__ h1, const float* __restrict__ root2,
    const float* __restrict__ theta2, const float* __restrict__ bias2,
    float* __restrict__ out2, float* __restrict__ P2, int N)
{
    __shared__ float sr[40], st[160], sb2[2];
    int tid = threadIdx.x;
    if (tid < 40) sr[tid] = root2[tid];
    if (tid >= 64 && tid < 224) st[tid - 64] = theta2[tid - 64];
    if (tid < 2) sb2[tid] = bias2[tid];
    __syncthreads();
    int n = blockIdx.x * 256 + tid;
    if (n >= N) return;
    float hv[20];
    const float4* hp = (const float4*)(h1 + (size_t)n * 20);
    #pragma unroll
    for (int q = 0; q < 5; ++q) {
        float4 v = hp[q];
        hv[q*4+0] = fmaxf(v.x, 0.f);
        hv[q*4+1] = fmaxf(v.y, 0.f);
        hv[q*4+2] = fmaxf(v.z, 0.f);
        hv[q*4+3] = fmaxf(v.w, 0.f);
    }
    float o0 = sb2[0], o1 = sb2[1];
    #pragma unroll
    for (int h = 0; h < 20; ++h) { o0 += hv[h]*sr[h*2]; o1 += hv[h]*sr[h*2+1]; }
    out2[(size_t)n*2 + 0] = o0;
    out2[(size_t)n*2 + 1] = o1;
    #pragma unroll
    for (int l = 0; l < 4; ++l) {
        float p0 = 0.f, p1 = 0.f;
        #pragma unroll
        for (int h = 0; h < 20; ++h) {
            p0 += hv[h]*st[l*40 + h*2];
            p1 += hv[h]*st[l*40 + h*2 + 1];
        }
        P2[(size_t)n*8 + l*2 + 0] = p0;
        P2[(size_t)n*8 + l*2 + 1] = p1;
    }
}

// ---------------- Kernel E: edge scatter layer 2 --------------------------------
__global__ __launch_bounds__(256) void edge_scatter2(
    const int* __restrict__ ei, const float4* __restrict__ wedge2,
    const float4* __restrict__ P2, float* __restrict__ out2, int E)
{
    int e = blockIdx.x * 256 + threadIdx.x;
    if (e >= E) return;
    int s = ei[e], d = ei[E + e];
    float4 w = wedge2[e];
    // P2 row = 8 floats = 2 float4: [l0j0 l0j1 l1j0 l1j1][l2j0 l2j1 l3j0 l3j1]
    float4 pa = P2[(size_t)s*2], pb = P2[(size_t)s*2 + 1];
    float y0 = w.x*pa.x + w.y*pa.z + w.z*pb.x + w.w*pb.z;
    float y1 = w.x*pa.y + w.y*pa.w + w.z*pb.y + w.w*pb.w;
    atomicAdd(out2 + (size_t)d*2 + 0, y0);
    atomicAdd(out2 + (size_t)d*2 + 1, y1);
    float4 qa = P2[(size_t)d*2], qb = P2[(size_t)d*2 + 1];
    float z0 = w.x*qa.x + w.y*qa.z + w.z*qb.x + w.w*qb.z;
    float z1 = w.x*qa.y + w.y*qa.w + w.z*qb.y + w.w*qb.w;
    atomicAdd(out2 + (size_t)s*2 + 0, z0);
    atomicAdd(out2 + (size_t)s*2 + 1, z1);
}

// ---------------- Kernel F: log_softmax over 2 classes --------------------------
__global__ __launch_bounds__(256) void logsoftmax_k(
    const float* __restrict__ out2, float* __restrict__ out, int N)
{
    int n = blockIdx.x * 256 + threadIdx.x;
    if (n >= N) return;
    float o0 = out2[(size_t)n*2], o1 = out2[(size_t)n*2 + 1];
    float m = fmaxf(o0, o1);
    float lse = m + logf(expf(o0 - m) + expf(o1 - m));
    out[(size_t)n*2]     = o0 - lse;
    out[(size_t)n*2 + 1] = o1 - lse;
}

extern "C" void kernel_launch(void* const* d_in, const int* in_sizes, int n_in,
                              void* d_out, int out_size, void* d_ws, size_t ws_size,
                              hipStream_t stream)
{
    const float* x     = (const float*)d_in[0];
    const int*   ei    = (const int*)d_in[1];
    const float* attr  = (const float*)d_in[2];
    const float* cut   = (const float*)d_in[3];
    const float* cw1   = (const float*)d_in[4];
    const float* cb1   = (const float*)d_in[5];
    const float* f1w1  = (const float*)d_in[6];
    const float* f1b1  = (const float*)d_in[7];
    const float* f2w1  = (const float*)d_in[8];
    const float* f2b1  = (const float*)d_in[9];
    const float* th1   = (const float*)d_in[10];
    const float* rt1   = (const float*)d_in[11];
    const float* bs1   = (const float*)d_in[12];
    const float* cw2   = (const float*)d_in[13];
    const float* cb2   = (const float*)d_in[14];
    const float* f1w2  = (const float*)d_in[15];
    const float* f1b2  = (const float*)d_in[16];
    const float* f2w2  = (const float*)d_in[17];
    const float* f2b2  = (const float*)d_in[18];
    const float* th2   = (const float*)d_in[19];
    const float* rt2   = (const float*)d_in[20];
    const float* bs2   = (const float*)d_in[21];

    const int N = in_sizes[0] / 64;
    const int E = in_sizes[1] / 2;

    float* ws     = (float*)d_ws;
    float* wedge1 = ws;                          // E*4
    float* wedge2 = wedge1 + (size_t)E * 4;      // E*4
    float* P1     = wedge2 + (size_t)E * 4;      // N*80
    float* h1     = P1     + (size_t)N * 80;     // N*20
    float* P2     = h1     + (size_t)N * 20;     // N*8
    float* o2     = P2     + (size_t)N * 8;      // N*2
    // total: 8*E + 110*N floats = 95.2 MB

    filter_kernel<<<(E + 255) / 256, 256, 0, stream>>>(
        attr, cut, cw1, cb1, f1w1, f1b1, f2w1, f2b1,
        cw2, cb2, f1w2, f1b2, f2w2, f2b2, wedge1, wedge2, E);

    node_prep1<<<(N + 7) / 8, 256, 0, stream>>>(x, rt1, th1, bs1, h1, P1, N);

    edge_scatter1<<<(E + 255) / 256, 256, 0, stream>>>(
        ei, (const float4*)wedge1, (const float4*)P1, h1, E);

    node_prep2<<<(N + 255) / 256, 256, 0, stream>>>(h1, rt2, th2, bs2, o2, P2, N);

    edge_scatter2<<<(E + 255) / 256, 256, 0, stream>>>(
        ei, (const float4*)wedge2, (const float4*)P2, o2, E);

    logsoftmax_k<<<(N + 255) / 256, 256, 0, stream>>>(o2, (float*)d_out, N);
}

// Round 2
// 1184.395 us; speedup vs baseline: 3.3260x; 3.3260x over previous
//
#include <hip/hip_runtime.h>
#include <math.h>

// Problem constants: F_IN=64, K=16, C=20, L=4, H1=20, H2=2
// N=100k nodes, E=1.6M undirected edges (3.2M directed after mirroring).

// ---------------- Kernel A: both filter nets for 1.6M unique edge attrs ---------
__global__ __launch_bounds__(256) void filter_kernel(
    const float* __restrict__ attr, const float* __restrict__ cutoffs,
    const float* __restrict__ cw1, const float* __restrict__ cb1,
    const float* __restrict__ f1w1, const float* __restrict__ f1b1,
    const float* __restrict__ f2w1, const float* __restrict__ f2b1,
    const float* __restrict__ cw2, const float* __restrict__ cb2,
    const float* __restrict__ f1w2, const float* __restrict__ f1b2,
    const float* __restrict__ f2w2, const float* __restrict__ f2b2,
    float* __restrict__ wedge1, float* __restrict__ wedge2, int E)
{
    __shared__ float s_cut[16];
    __shared__ float s_w[2][344]; // cw(120) cb(20) f1w(160) f1b(8) f2w(32) f2b(4)
    int tid = threadIdx.x;
    if (tid < 16) s_cut[tid] = cutoffs[tid];
    for (int i = tid; i < 344; i += 256) {
        float v1, v2;
        if (i < 120)      { v1 = cw1[i];       v2 = cw2[i]; }
        else if (i < 140) { v1 = cb1[i-120];   v2 = cb2[i-120]; }
        else if (i < 300) { v1 = f1w1[i-140];  v2 = f1w2[i-140]; }
        else if (i < 308) { v1 = f1b1[i-300];  v2 = f1b2[i-300]; }
        else if (i < 340) { v1 = f2w1[i-308];  v2 = f2w2[i-308]; }
        else              { v1 = f2b1[i-340];  v2 = f2b2[i-340]; }
        s_w[0][i] = v1; s_w[1][i] = v2;
    }
    __syncthreads();
    int e = blockIdx.x * 256 + tid;
    if (e >= E) return;
    float a = attr[e];
    float dp[18], sp[18];
    dp[0] = 0.f; sp[0] = 0.f; dp[17] = 0.f; sp[17] = 0.f;
    #pragma unroll
    for (int k = 0; k < 16; ++k) {
        float d = a - s_cut[k];
        dp[k+1] = d;
        sp[k+1] = d > 0.f ? 1.f : 0.f;
    }
    #pragma unroll
    for (int layer = 0; layer < 2; ++layer) {
        const float* W = s_w[layer];
        float h[20];
        #pragma unroll
        for (int c = 0; c < 20; ++c) {
            float w00 = W[c*6+0], w01 = W[c*6+1], w02 = W[c*6+2];
            float w10 = W[c*6+3], w11 = W[c*6+4], w12 = W[c*6+5];
            float b = W[120 + c];
            float m = -1e30f;
            #pragma unroll
            for (int k = 0; k < 16; ++k) {
                float v = b + dp[k]*w00 + dp[k+1]*w01 + dp[k+2]*w02
                            + sp[k]*w10 + sp[k+1]*w11 + sp[k+2]*w12;
                m = fmaxf(m, v);
            }
            h[c] = fmaxf(m, 0.f);
        }
        float g[8];
        #pragma unroll
        for (int j = 0; j < 8; ++j) {
            float t = W[300 + j];
            #pragma unroll
            for (int c = 0; c < 20; ++c) t += W[140 + j*20 + c] * h[c];
            g[j] = fmaxf(t, 0.f);
        }
        float4 wo;
        float* wp = (float*)&wo;
        #pragma unroll
        for (int l = 0; l < 4; ++l) {
            float t = W[340 + l];
            #pragma unroll
            for (int j = 0; j < 8; ++j) t += W[308 + l*8 + j] * g[j];
            wp[l] = fmaxf(t, 0.f);
        }
        float4* dstp = (float4*)(layer == 0 ? wedge1 : wedge2);
        dstp[e] = wo;
    }
}

// ---------------- Kernel B: h1 = x@root1 + bias1 ; P1[n,l,h] = x[n]@theta1[l] ----
__global__ __launch_bounds__(256) void node_prep1(
    const float* __restrict__ x, const float* __restrict__ root1,
    const float* __restrict__ theta1, const float* __restrict__ bias1,
    float* __restrict__ h1, float* __restrict__ P1, int N)
{
    __shared__ float Ws[64 * 100];
    __shared__ float xs[8 * 64];
    __shared__ float sb[20];
    int tid = threadIdx.x;
    for (int i = tid; i < 6400; i += 256) {
        int f = i / 100, c = i % 100;
        float v;
        if (c < 20) v = root1[f*20 + c];
        else { int l = (c-20)/20, hh = (c-20)%20; v = theta1[l*1280 + f*20 + hh]; }
        Ws[i] = v;
    }
    if (tid < 20) sb[tid] = bias1[tid];
    int nb = blockIdx.x * 8;
    for (int i = tid; i < 512; i += 256) {
        int nl = i >> 6, f = i & 63;
        int n = nb + nl;
        xs[i] = (n < N) ? x[(size_t)n*64 + f] : 0.f;
    }
    __syncthreads();
    for (int i = tid; i < 800; i += 256) {
        int nl = i / 100, c = i % 100;
        int n = nb + nl;
        if (n >= N) continue;
        float acc = 0.f;
        #pragma unroll 16
        for (int f = 0; f < 64; ++f) acc += xs[nl*64 + f] * Ws[f*100 + c];
        if (c < 20) h1[(size_t)n*20 + c] = acc + sb[c];
        else        P1[(size_t)n*80 + (c - 20)] = acc;
    }
}

// ---------------- Kernel C: build capacity-slotted incidence lists --------------
// For each undirected edge j (s,d): insert eid j into both endpoints' lists.
// Gather later recovers the neighbor as nbr = ei[j] + ei[E+j] - n.
__global__ __launch_bounds__(256) void fill_kernel(
    const int* __restrict__ ei, int* __restrict__ cnt,
    unsigned* __restrict__ slots, int E, int CAP)
{
    int j = blockIdx.x * 256 + threadIdx.x;
    if (j >= E) return;
    int s = ei[j], d = ei[E + j];
    int p = atomicAdd(&cnt[d], 1);
    if (p < CAP) slots[(size_t)d * CAP + p] = (unsigned)j;
    int q = atomicAdd(&cnt[s], 1);
    if (q < CAP) slots[(size_t)s * CAP + q] = (unsigned)j;
}

// ---------------- Kernel D: gather layer 1 (no atomics) -------------------------
// 5 threads per node; thread q owns h-components [q*4, q*4+4).
__global__ __launch_bounds__(256) void gather1_kernel(
    const int* __restrict__ ei, const int* __restrict__ cnt,
    const unsigned* __restrict__ slots, const float4* __restrict__ wedge1,
    const float* __restrict__ P1, float* __restrict__ h1, int N, int E, int CAP)
{
    int t = blockIdx.x * 256 + threadIdx.x;
    if (t >= N * 5) return;
    int n = t / 5, q = t % 5;
    int c = cnt[n]; if (c > CAP) c = CAP;
    const unsigned* sl = slots + (size_t)n * CAP;
    float4 acc = make_float4(0.f, 0.f, 0.f, 0.f);
    for (int i = 0; i < c; ++i) {
        unsigned j = sl[i];
        int s = ei[j], d = ei[E + j];
        int nbr = s + d - n;
        float4 w = wedge1[j];
        const float4* Pr = (const float4*)(P1 + (size_t)nbr * 80);
        float4 a0 = Pr[0*5 + q], a1 = Pr[1*5 + q], a2 = Pr[2*5 + q], a3 = Pr[3*5 + q];
        acc.x += w.x*a0.x + w.y*a1.x + w.z*a2.x + w.w*a3.x;
        acc.y += w.x*a0.y + w.y*a1.y + w.z*a2.y + w.w*a3.y;
        acc.z += w.x*a0.z + w.y*a1.z + w.z*a2.z + w.w*a3.z;
        acc.w += w.x*a0.w + w.y*a1.w + w.z*a2.w + w.w*a3.w;
    }
    float4* H = (float4*)h1;
    float4 base = H[(size_t)n*5 + q];
    base.x += acc.x; base.y += acc.y; base.z += acc.z; base.w += acc.w;
    H[(size_t)n*5 + q] = base;
}

// ---------------- Kernel E: relu(h1); o2 = r@root2+bias2; P2[n,l,j] -------------
__global__ __launch_bounds__(256) void node_prep2(
    const float* __restrict__ h1, const float* __restrict__ root2,
    const float* __restrict__ theta2, const float* __restrict__ bias2,
    float* __restrict__ out2, float* __restrict__ P2, int N)
{
    __shared__ float sr[40], st[160], sb2[2];
    int tid = threadIdx.x;
    if (tid < 40) sr[tid] = root2[tid];
    if (tid >= 64 && tid < 224) st[tid - 64] = theta2[tid - 64];
    if (tid < 2) sb2[tid] = bias2[tid];
    __syncthreads();
    int n = blockIdx.x * 256 + tid;
    if (n >= N) return;
    float hv[20];
    const float4* hp = (const float4*)(h1 + (size_t)n * 20);
    #pragma unroll
    for (int q = 0; q < 5; ++q) {
        float4 v = hp[q];
        hv[q*4+0] = fmaxf(v.x, 0.f);
        hv[q*4+1] = fmaxf(v.y, 0.f);
        hv[q*4+2] = fmaxf(v.z, 0.f);
        hv[q*4+3] = fmaxf(v.w, 0.f);
    }
    float o0 = sb2[0], o1 = sb2[1];
    #pragma unroll
    for (int h = 0; h < 20; ++h) { o0 += hv[h]*sr[h*2]; o1 += hv[h]*sr[h*2+1]; }
    out2[(size_t)n*2 + 0] = o0;
    out2[(size_t)n*2 + 1] = o1;
    #pragma unroll
    for (int l = 0; l < 4; ++l) {
        float p0 = 0.f, p1 = 0.f;
        #pragma unroll
        for (int h = 0; h < 20; ++h) {
            p0 += hv[h]*st[l*40 + h*2];
            p1 += hv[h]*st[l*40 + h*2 + 1];
        }
        P2[(size_t)n*8 + l*2 + 0] = p0;
        P2[(size_t)n*8 + l*2 + 1] = p1;
    }
}

// ---------------- Kernel F: gather layer 2 + fused log_softmax ------------------
__global__ __launch_bounds__(256) void gather2_lsm_kernel(
    const int* __restrict__ ei, const int* __restrict__ cnt,
    const unsigned* __restrict__ slots, const float4* __restrict__ wedge2,
    const float4* __restrict__ P2, const float* __restrict__ o2,
    float* __restrict__ out, int N, int E, int CAP)
{
    int n = blockIdx.x * 256 + threadIdx.x;
    if (n >= N) return;
    int c = cnt[n]; if (c > CAP) c = CAP;
    const unsigned* sl = slots + (size_t)n * CAP;
    float o0 = o2[(size_t)n*2], o1 = o2[(size_t)n*2 + 1];
    for (int i = 0; i < c; ++i) {
        unsigned j = sl[i];
        int s = ei[j], d = ei[E + j];
        int nbr = s + d - n;
        float4 w = wedge2[j];
        float4 pa = P2[(size_t)nbr*2], pb = P2[(size_t)nbr*2 + 1];
        o0 += w.x*pa.x + w.y*pa.z + w.z*pb.x + w.w*pb.z;
        o1 += w.x*pa.y + w.y*pa.w + w.z*pb.y + w.w*pb.w;
    }
    float m = fmaxf(o0, o1);
    float lse = m + logf(expf(o0 - m) + expf(o1 - m));
    out[(size_t)n*2]     = o0 - lse;
    out[(size_t)n*2 + 1] = o1 - lse;
}

// ================= Fallback path (atomic scatter) if workspace too small ========
__global__ __launch_bounds__(256) void edge_scatter1(
    const int* __restrict__ ei, const float4* __restrict__ wedge1,
    const float4* __restrict__ P1, float* __restrict__ h1, int E)
{
    int e = blockIdx.x * 256 + threadIdx.x;
    if (e >= E) return;
    int s = ei[e], d = ei[E + e];
    float4 w = wedge1[e];
    const float4* Ps = P1 + (size_t)s * 20;
    const float4* Pd = P1 + (size_t)d * 20;
    float* Hs = h1 + (size_t)s * 20;
    float* Hd = h1 + (size_t)d * 20;
    #pragma unroll
    for (int q = 0; q < 5; ++q) {
        float4 a0 = Ps[q], a1 = Ps[5+q], a2 = Ps[10+q], a3 = Ps[15+q];
        atomicAdd(Hd + q*4 + 0, w.x*a0.x + w.y*a1.x + w.z*a2.x + w.w*a3.x);
        atomicAdd(Hd + q*4 + 1, w.x*a0.y + w.y*a1.y + w.z*a2.y + w.w*a3.y);
        atomicAdd(Hd + q*4 + 2, w.x*a0.z + w.y*a1.z + w.z*a2.z + w.w*a3.z);
        atomicAdd(Hd + q*4 + 3, w.x*a0.w + w.y*a1.w + w.z*a2.w + w.w*a3.w);
        float4 b0 = Pd[q], b1 = Pd[5+q], b2 = Pd[10+q], b3 = Pd[15+q];
        atomicAdd(Hs + q*4 + 0, w.x*b0.x + w.y*b1.x + w.z*b2.x + w.w*b3.x);
        atomicAdd(Hs + q*4 + 1, w.x*b0.y + w.y*b1.y + w.z*b2.y + w.w*b3.y);
        atomicAdd(Hs + q*4 + 2, w.x*b0.z + w.y*b1.z + w.z*b2.z + w.w*b3.z);
        atomicAdd(Hs + q*4 + 3, w.x*b0.w + w.y*b1.w + w.z*b2.w + w.w*b3.w);
    }
}

__global__ __launch_bounds__(256) void edge_scatter2(
    const int* __restrict__ ei, const float4* __restrict__ wedge2,
    const float4* __restrict__ P2, float* __restrict__ out2, int E)
{
    int e = blockIdx.x * 256 + threadIdx.x;
    if (e >= E) return;
    int s = ei[e], d = ei[E + e];
    float4 w = wedge2[e];
    float4 pa = P2[(size_t)s*2], pb = P2[(size_t)s*2 + 1];
    float y0 = w.x*pa.x + w.y*pa.z + w.z*pb.x + w.w*pb.z;
    float y1 = w.x*pa.y + w.y*pa.w + w.z*pb.y + w.w*pb.w;
    atomicAdd(out2 + (size_t)d*2 + 0, y0);
    atomicAdd(out2 + (size_t)d*2 + 1, y1);
    float4 qa = P2[(size_t)d*2], qb = P2[(size_t)d*2 + 1];
    float z0 = w.x*qa.x + w.y*qa.z + w.z*qb.x + w.w*qb.z;
    float z1 = w.x*qa.y + w.y*qa.w + w.z*qb.y + w.w*qb.w;
    atomicAdd(out2 + (size_t)s*2 + 0, z0);
    atomicAdd(out2 + (size_t)s*2 + 1, z1);
}

__global__ __launch_bounds__(256) void logsoftmax_k(
    const float* __restrict__ out2, float* __restrict__ out, int N)
{
    int n = blockIdx.x * 256 + threadIdx.x;
    if (n >= N) return;
    float o0 = out2[(size_t)n*2], o1 = out2[(size_t)n*2 + 1];
    float m = fmaxf(o0, o1);
    float lse = m + logf(expf(o0 - m) + expf(o1 - m));
    out[(size_t)n*2]     = o0 - lse;
    out[(size_t)n*2 + 1] = o1 - lse;
}

extern "C" void kernel_launch(void* const* d_in, const int* in_sizes, int n_in,
                              void* d_out, int out_size, void* d_ws, size_t ws_size,
                              hipStream_t stream)
{
    const float* x     = (const float*)d_in[0];
    const int*   ei    = (const int*)d_in[1];
    const float* attr  = (const float*)d_in[2];
    const float* cut   = (const float*)d_in[3];
    const float* cw1   = (const float*)d_in[4];
    const float* cb1   = (const float*)d_in[5];
    const float* f1w1  = (const float*)d_in[6];
    const float* f1b1  = (const float*)d_in[7];
    const float* f2w1  = (const float*)d_in[8];
    const float* f2b1  = (const float*)d_in[9];
    const float* th1   = (const float*)d_in[10];
    const float* rt1   = (const float*)d_in[11];
    const float* bs1   = (const float*)d_in[12];
    const float* cw2   = (const float*)d_in[13];
    const float* cb2   = (const float*)d_in[14];
    const float* f1w2  = (const float*)d_in[15];
    const float* f1b2  = (const float*)d_in[16];
    const float* f2w2  = (const float*)d_in[17];
    const float* f2b2  = (const float*)d_in[18];
    const float* th2   = (const float*)d_in[19];
    const float* rt2   = (const float*)d_in[20];
    const float* bs2   = (const float*)d_in[21];

    const int N = in_sizes[0] / 64;
    const int E = in_sizes[1] / 2;

    float* ws     = (float*)d_ws;
    float* wedge1 = ws;                          // E*4
    float* wedge2 = wedge1 + (size_t)E * 4;      // E*4
    float* P1     = wedge2 + (size_t)E * 4;      // N*80
    float* h1     = P1     + (size_t)N * 80;     // N*20
    float* P2     = h1     + (size_t)N * 20;     // N*8
    float* o2     = P2     + (size_t)N * 8;      // N*2
    int*   cnt    = (int*)(o2 + (size_t)N * 2);  // N
    unsigned* slots = (unsigned*)(cnt + N);      // N*CAP

    size_t base_bytes = ((size_t)8*E + 111*(size_t)N) * 4;
    int CAP = 0;
    if (ws_size > base_bytes) {
        size_t cap_elems = (ws_size - base_bytes) / ((size_t)N * 4);
        CAP = (int)(cap_elems > 128 ? 128 : cap_elems);
    }

    filter_kernel<<<(E + 255) / 256, 256, 0, stream>>>(
        attr, cut, cw1, cb1, f1w1, f1b1, f2w1, f2b1,
        cw2, cb2, f1w2, f1b2, f2w2, f2b2, wedge1, wedge2, E);

    node_prep1<<<(N + 7) / 8, 256, 0, stream>>>(x, rt1, th1, bs1, h1, P1, N);

    if (CAP >= 72) {
        // Gather path: no fp32 atomics anywhere.
        hipMemsetAsync(cnt, 0, (size_t)N * 4, stream);
        fill_kernel<<<(E + 255) / 256, 256, 0, stream>>>(ei, cnt, slots, E, CAP);
        gather1_kernel<<<(N * 5 + 255) / 256, 256, 0, stream>>>(
            ei, cnt, slots, (const float4*)wedge1, P1, h1, N, E, CAP);
        node_prep2<<<(N + 255) / 256, 256, 0, stream>>>(h1, rt2, th2, bs2, o2, P2, N);
        gather2_lsm_kernel<<<(N + 255) / 256, 256, 0, stream>>>(
            ei, cnt, slots, (const float4*)wedge2, (const float4*)P2, o2,
            (float*)d_out, N, E, CAP);
    } else {
        // Fallback: atomic scatter (correct but slow).
        edge_scatter1<<<(E + 255) / 256, 256, 0, stream>>>(
            ei, (const float4*)wedge1, (const float4*)P1, h1, E);
        node_prep2<<<(N + 255) / 256, 256, 0, stream>>>(h1, rt2, th2, bs2, o2, P2, N);
        edge_scatter2<<<(E + 255) / 256, 256, 0, stream>>>(
            ei, (const float4*)wedge2, (const float4*)P2, o2, E);
        logsoftmax_k<<<(N + 255) / 256, 256, 0, stream>>>(o2, (float*)d_out, N);
    }
}

// Round 3
// 917.871 us; speedup vs baseline: 4.2918x; 1.2904x over previous
//
#include <hip/hip_runtime.h>
#include <hip/hip_fp16.h>
#include <math.h>

// Problem constants: F_IN=64, K=16, C=20, L=4, H1=20, H2=2
// N=100k nodes, E=1.6M undirected edges (3.2M directed after mirroring).

// ---------------- K1: filter nets (both layers) + incidence-list fill -----------
// Fill's 3.2M int atomics hide under the filter net's VALU work.
__global__ __launch_bounds__(256) void filter_fill_kernel(
    const float* __restrict__ attr, const float* __restrict__ cutoffs,
    const float* __restrict__ cw1, const float* __restrict__ cb1,
    const float* __restrict__ f1w1, const float* __restrict__ f1b1,
    const float* __restrict__ f2w1, const float* __restrict__ f2b1,
    const float* __restrict__ cw2, const float* __restrict__ cb2,
    const float* __restrict__ f1w2, const float* __restrict__ f1b2,
    const float* __restrict__ f2w2, const float* __restrict__ f2b2,
    const int* __restrict__ ei, int* __restrict__ cnt, unsigned* __restrict__ slots,
    float* __restrict__ wedge1, float* __restrict__ wedge2, int E, int CAP, int doFill)
{
    __shared__ float s_cut[16];
    __shared__ float s_w[2][344]; // cw(120) cb(20) f1w(160) f1b(8) f2w(32) f2b(4)
    int tid = threadIdx.x;
    if (tid < 16) s_cut[tid] = cutoffs[tid];
    for (int i = tid; i < 344; i += 256) {
        float v1, v2;
        if (i < 120)      { v1 = cw1[i];       v2 = cw2[i]; }
        else if (i < 140) { v1 = cb1[i-120];   v2 = cb2[i-120]; }
        else if (i < 300) { v1 = f1w1[i-140];  v2 = f1w2[i-140]; }
        else if (i < 308) { v1 = f1b1[i-300];  v2 = f1b2[i-300]; }
        else if (i < 340) { v1 = f2w1[i-308];  v2 = f2w2[i-308]; }
        else              { v1 = f2b1[i-340];  v2 = f2b2[i-340]; }
        s_w[0][i] = v1; s_w[1][i] = v2;
    }
    __syncthreads();
    int e = blockIdx.x * 256 + tid;
    if (e >= E) return;

    // Kick off the incidence inserts early so atomic latency overlaps compute.
    if (doFill) {
        int s = ei[e], d = ei[E + e];
        int p = atomicAdd(&cnt[d], 1);
        if (p < CAP) slots[(size_t)d * CAP + p] = (unsigned)e;
        int p2 = atomicAdd(&cnt[s], 1);
        if (p2 < CAP) slots[(size_t)s * CAP + p2] = (unsigned)e;
    }

    float a = attr[e];
    float dp[18], sp[18];
    dp[0] = 0.f; sp[0] = 0.f; dp[17] = 0.f; sp[17] = 0.f;
    #pragma unroll
    for (int k = 0; k < 16; ++k) {
        float d = a - s_cut[k];
        dp[k+1] = d;
        sp[k+1] = d > 0.f ? 1.f : 0.f;
    }
    #pragma unroll
    for (int layer = 0; layer < 2; ++layer) {
        const float* W = s_w[layer];
        float h[20];
        #pragma unroll
        for (int c = 0; c < 20; ++c) {
            float w00 = W[c*6+0], w01 = W[c*6+1], w02 = W[c*6+2];
            float w10 = W[c*6+3], w11 = W[c*6+4], w12 = W[c*6+5];
            float b = W[120 + c];
            float m = -1e30f;
            #pragma unroll
            for (int k = 0; k < 16; ++k) {
                float v = b + dp[k]*w00 + dp[k+1]*w01 + dp[k+2]*w02
                            + sp[k]*w10 + sp[k+1]*w11 + sp[k+2]*w12;
                m = fmaxf(m, v);
            }
            h[c] = fmaxf(m, 0.f);
        }
        float g[8];
        #pragma unroll
        for (int j = 0; j < 8; ++j) {
            float t = W[300 + j];
            #pragma unroll
            for (int c = 0; c < 20; ++c) t += W[140 + j*20 + c] * h[c];
            g[j] = fmaxf(t, 0.f);
        }
        float4 wo;
        float* wp = (float*)&wo;
        #pragma unroll
        for (int l = 0; l < 4; ++l) {
            float t = W[340 + l];
            #pragma unroll
            for (int j = 0; j < 8; ++j) t += W[308 + l*8 + j] * g[j];
            wp[l] = fmaxf(t, 0.f);
        }
        float4* dstp = (float4*)(layer == 0 ? wedge1 : wedge2);
        dstp[e] = wo;
    }
}

// ---------------- K2: h1 = x@root1+bias1 ; x_h = fp16(x) ------------------------
// 8 lanes per node; lane q owns features [8q, 8q+8).
__global__ __launch_bounds__(256) void node_prep1b(
    const float* __restrict__ x, const float* __restrict__ root1,
    const float* __restrict__ bias1, float* __restrict__ h1,
    __half* __restrict__ x_h, int N)
{
    __shared__ float r1s[64 * 21];  // f-stride 21 to break bank alignment
    __shared__ float sb[20];
    int tid = threadIdx.x;
    for (int i = tid; i < 1280; i += 256) {
        int f = i / 20, h = i % 20;
        r1s[f*21 + h] = root1[i];
    }
    if (tid < 20) sb[tid] = bias1[tid];
    __syncthreads();
    int t = blockIdx.x * 256 + tid;
    int n = t >> 3, q = t & 7;
    if (n >= N) return;
    const float4* xr = (const float4*)(x + (size_t)n*64 + q*8);
    float4 va = xr[0], vb = xr[1];
    float xf[8] = {va.x, va.y, va.z, va.w, vb.x, vb.y, vb.z, vb.w};
    __half hh[8];
    #pragma unroll
    for (int j = 0; j < 8; ++j) hh[j] = __float2half(xf[j]);
    *(uint4*)(x_h + (size_t)n*64 + q*8) = *(const uint4*)hh;
    float p[20];
    #pragma unroll
    for (int h = 0; h < 20; ++h) p[h] = 0.f;
    #pragma unroll
    for (int j = 0; j < 8; ++j) {
        float xv = xf[j];
        int base = (q*8 + j) * 21;
        #pragma unroll
        for (int h = 0; h < 20; ++h) p[h] += xv * r1s[base + h];
    }
    #pragma unroll
    for (int m = 1; m < 8; m <<= 1) {
        #pragma unroll
        for (int h = 0; h < 20; ++h) p[h] += __shfl_xor(p[h], m, 64);
    }
    if (q < 5) {
        float4 o;
        o.x = p[q*4+0] + sb[q*4+0];
        o.y = p[q*4+1] + sb[q*4+1];
        o.z = p[q*4+2] + sb[q*4+2];
        o.w = p[q*4+3] + sb[q*4+3];
        *(float4*)(h1 + (size_t)n*20 + q*4) = o;
    }
}

// ---------------- K3: gather x_h (1 line/edge), theta1-apply, fused node_prep2 --
// 8 lanes per node. Edge loop: acc[l][f-chunk] += w_l * x_h[nbr][f-chunk].
// Epilogue: p = acc @ theta1 (LDS), butterfly-reduce, relu(+h1 base),
// then o2 = r@root2+bias2, P2 = r@theta2 — no h1 round-trip, no atomics.
__global__ __launch_bounds__(256) void gather1_fused(
    const int* __restrict__ ei, const int* __restrict__ cnt,
    const unsigned* __restrict__ slots, const float4* __restrict__ wedge1,
    const __half* __restrict__ x_h, const float* __restrict__ h1,
    const float* __restrict__ theta1,
    const float* __restrict__ root2, const float* __restrict__ theta2,
    const float* __restrict__ bias2,
    float* __restrict__ o2, float* __restrict__ P2,
    int N, int E, int CAP)
{
    __shared__ float th[4 * 64 * 21];  // 21.5 KB, f-stride 21
    __shared__ float w2s[200];         // [o][h]: o<2 root2 col, o>=2 theta2
    __shared__ float w2b[2];
    int tid = threadIdx.x;
    for (int i = tid; i < 5120; i += 256) {
        int l = i / 1280, f = (i / 20) % 64, h = i % 20;
        th[(l*64 + f)*21 + h] = theta1[i];
    }
    for (int i = tid; i < 200; i += 256) {
        int o = i / 20, h = i % 20;
        float v;
        if (o < 2) v = root2[h*2 + o];
        else { int l = (o-2) >> 1, jj = (o-2) & 1; v = theta2[l*40 + h*2 + jj]; }
        w2s[i] = v;
    }
    if (tid < 2) w2b[tid] = bias2[tid];
    __syncthreads();
    int t = blockIdx.x * 256 + tid;
    int n = t >> 3, q = t & 7;
    if (n >= N) return;
    int c = cnt[n]; if (c > CAP) c = CAP;
    const unsigned* sl = slots + (size_t)n * CAP;
    float acc[4][8];
    #pragma unroll
    for (int l = 0; l < 4; ++l)
        #pragma unroll
        for (int j = 0; j < 8; ++j) acc[l][j] = 0.f;
    for (int i = 0; i < c; ++i) {
        unsigned j = sl[i];
        int nbr = ei[j] + ei[E + j] - n;
        float4 w = wedge1[j];
        uint4 hx = *(const uint4*)(x_h + (size_t)nbr*64 + q*8);
        const __half* hp = (const __half*)&hx;
        float xf[8];
        #pragma unroll
        for (int j2 = 0; j2 < 8; ++j2) xf[j2] = __half2float(hp[j2]);
        #pragma unroll
        for (int j2 = 0; j2 < 8; ++j2) {
            acc[0][j2] += w.x * xf[j2];
            acc[1][j2] += w.y * xf[j2];
            acc[2][j2] += w.z * xf[j2];
            acc[3][j2] += w.w * xf[j2];
        }
    }
    float p[20];
    #pragma unroll
    for (int h = 0; h < 20; ++h) p[h] = 0.f;
    #pragma unroll
    for (int l = 0; l < 4; ++l) {
        #pragma unroll
        for (int j2 = 0; j2 < 8; ++j2) {
            float a = acc[l][j2];
            int base = ((l << 6) + (q << 3) + j2) * 21;
            #pragma unroll
            for (int h = 0; h < 20; ++h) p[h] += a * th[base + h];
        }
    }
    #pragma unroll
    for (int m = 1; m < 8; m <<= 1) {
        #pragma unroll
        for (int h = 0; h < 20; ++h) p[h] += __shfl_xor(p[h], m, 64);
    }
    // relu(base + agg)
    const float4* hb = (const float4*)(h1 + (size_t)n*20);
    float hv[20];
    #pragma unroll
    for (int qq = 0; qq < 5; ++qq) {
        float4 v = hb[qq];
        hv[qq*4+0] = fmaxf(p[qq*4+0] + v.x, 0.f);
        hv[qq*4+1] = fmaxf(p[qq*4+1] + v.y, 0.f);
        hv[qq*4+2] = fmaxf(p[qq*4+2] + v.z, 0.f);
        hv[qq*4+3] = fmaxf(p[qq*4+3] + v.w, 0.f);
    }
    // 10 outputs: o<2 -> o2, o>=2 -> P2
    for (int o = q; o < 10; o += 8) {
        float v = (o < 2) ? w2b[o] : 0.f;
        #pragma unroll
        for (int h = 0; h < 20; ++h) v += hv[h] * w2s[o*20 + h];
        if (o < 2) o2[(size_t)n*2 + o] = v;
        else       P2[(size_t)n*8 + (o - 2)] = v;
    }
}

// ---------------- K4: gather layer 2 + fused log_softmax ------------------------
__global__ __launch_bounds__(256) void gather2_lsm_kernel(
    const int* __restrict__ ei, const int* __restrict__ cnt,
    const unsigned* __restrict__ slots, const float4* __restrict__ wedge2,
    const float4* __restrict__ P2, const float* __restrict__ o2,
    float* __restrict__ out, int N, int E, int CAP)
{
    int n = blockIdx.x * 256 + threadIdx.x;
    if (n >= N) return;
    int c = cnt[n]; if (c > CAP) c = CAP;
    const unsigned* sl = slots + (size_t)n * CAP;
    float o0 = o2[(size_t)n*2], o1 = o2[(size_t)n*2 + 1];
    for (int i = 0; i < c; ++i) {
        unsigned j = sl[i];
        int s = ei[j], d = ei[E + j];
        int nbr = s + d - n;
        float4 w = wedge2[j];
        float4 pa = P2[(size_t)nbr*2], pb = P2[(size_t)nbr*2 + 1];
        o0 += w.x*pa.x + w.y*pa.z + w.z*pb.x + w.w*pb.z;
        o1 += w.x*pa.y + w.y*pa.w + w.z*pb.y + w.w*pb.w;
    }
    float m = fmaxf(o0, o1);
    float lse = m + logf(expf(o0 - m) + expf(o1 - m));
    out[(size_t)n*2]     = o0 - lse;
    out[(size_t)n*2 + 1] = o1 - lse;
}

// ================= Fallback path (atomic scatter) if workspace too small ========
__global__ __launch_bounds__(256) void node_prep1(
    const float* __restrict__ x, const float* __restrict__ root1,
    const float* __restrict__ theta1, const float* __restrict__ bias1,
    float* __restrict__ h1, float* __restrict__ P1, int N)
{
    __shared__ float Ws[64 * 100];
    __shared__ float xs[8 * 64];
    __shared__ float sb[20];
    int tid = threadIdx.x;
    for (int i = tid; i < 6400; i += 256) {
        int f = i / 100, c = i % 100;
        float v;
        if (c < 20) v = root1[f*20 + c];
        else { int l = (c-20)/20, hh = (c-20)%20; v = theta1[l*1280 + f*20 + hh]; }
        Ws[i] = v;
    }
    if (tid < 20) sb[tid] = bias1[tid];
    int nb = blockIdx.x * 8;
    for (int i = tid; i < 512; i += 256) {
        int nl = i >> 6, f = i & 63;
        int n = nb + nl;
        xs[i] = (n < N) ? x[(size_t)n*64 + f] : 0.f;
    }
    __syncthreads();
    for (int i = tid; i < 800; i += 256) {
        int nl = i / 100, c = i % 100;
        int n = nb + nl;
        if (n >= N) continue;
        float acc = 0.f;
        #pragma unroll 16
        for (int f = 0; f < 64; ++f) acc += xs[nl*64 + f] * Ws[f*100 + c];
        if (c < 20) h1[(size_t)n*20 + c] = acc + sb[c];
        else        P1[(size_t)n*80 + (c - 20)] = acc;
    }
}

__global__ __launch_bounds__(256) void edge_scatter1(
    const int* __restrict__ ei, const float4* __restrict__ wedge1,
    const float4* __restrict__ P1, float* __restrict__ h1, int E)
{
    int e = blockIdx.x * 256 + threadIdx.x;
    if (e >= E) return;
    int s = ei[e], d = ei[E + e];
    float4 w = wedge1[e];
    const float4* Ps = P1 + (size_t)s * 20;
    const float4* Pd = P1 + (size_t)d * 20;
    float* Hs = h1 + (size_t)s * 20;
    float* Hd = h1 + (size_t)d * 20;
    #pragma unroll
    for (int q = 0; q < 5; ++q) {
        float4 a0 = Ps[q], a1 = Ps[5+q], a2 = Ps[10+q], a3 = Ps[15+q];
        atomicAdd(Hd + q*4 + 0, w.x*a0.x + w.y*a1.x + w.z*a2.x + w.w*a3.x);
        atomicAdd(Hd + q*4 + 1, w.x*a0.y + w.y*a1.y + w.z*a2.y + w.w*a3.y);
        atomicAdd(Hd + q*4 + 2, w.x*a0.z + w.y*a1.z + w.z*a2.z + w.w*a3.z);
        atomicAdd(Hd + q*4 + 3, w.x*a0.w + w.y*a1.w + w.z*a2.w + w.w*a3.w);
        float4 b0 = Pd[q], b1 = Pd[5+q], b2 = Pd[10+q], b3 = Pd[15+q];
        atomicAdd(Hs + q*4 + 0, w.x*b0.x + w.y*b1.x + w.z*b2.x + w.w*b3.x);
        atomicAdd(Hs + q*4 + 1, w.x*b0.y + w.y*b1.y + w.z*b2.y + w.w*b3.y);
        atomicAdd(Hs + q*4 + 2, w.x*b0.z + w.y*b1.z + w.z*b2.z + w.w*b3.z);
        atomicAdd(Hs + q*4 + 3, w.x*b0.w + w.y*b1.w + w.z*b2.w + w.w*b3.w);
    }
}

__global__ __launch_bounds__(256) void node_prep2(
    const float* __restrict__ h1, const float* __restrict__ root2,
    const float* __restrict__ theta2, const float* __restrict__ bias2,
    float* __restrict__ out2, float* __restrict__ P2, int N)
{
    __shared__ float sr[40], st[160], sb2[2];
    int tid = threadIdx.x;
    if (tid < 40) sr[tid] = root2[tid];
    if (tid >= 64 && tid < 224) st[tid - 64] = theta2[tid - 64];
    if (tid < 2) sb2[tid] = bias2[tid];
    __syncthreads();
    int n = blockIdx.x * 256 + tid;
    if (n >= N) return;
    float hv[20];
    const float4* hp = (const float4*)(h1 + (size_t)n * 20);
    #pragma unroll
    for (int q = 0; q < 5; ++q) {
        float4 v = hp[q];
        hv[q*4+0] = fmaxf(v.x, 0.f);
        hv[q*4+1] = fmaxf(v.y, 0.f);
        hv[q*4+2] = fmaxf(v.z, 0.f);
        hv[q*4+3] = fmaxf(v.w, 0.f);
    }
    float o0 = sb2[0], o1 = sb2[1];
    #pragma unroll
    for (int h = 0; h < 20; ++h) { o0 += hv[h]*sr[h*2]; o1 += hv[h]*sr[h*2+1]; }
    out2[(size_t)n*2 + 0] = o0;
    out2[(size_t)n*2 + 1] = o1;
    #pragma unroll
    for (int l = 0; l < 4; ++l) {
        float p0 = 0.f, p1 = 0.f;
        #pragma unroll
        for (int h = 0; h < 20; ++h) {
            p0 += hv[h]*st[l*40 + h*2];
            p1 += hv[h]*st[l*40 + h*2 + 1];
        }
        P2[(size_t)n*8 + l*2 + 0] = p0;
        P2[(size_t)n*8 + l*2 + 1] = p1;
    }
}

__global__ __launch_bounds__(256) void edge_scatter2(
    const int* __restrict__ ei, const float4* __restrict__ wedge2,
    const float4* __restrict__ P2, float* __restrict__ out2, int E)
{
    int e = blockIdx.x * 256 + threadIdx.x;
    if (e >= E) return;
    int s = ei[e], d = ei[E + e];
    float4 w = wedge2[e];
    float4 pa = P2[(size_t)s*2], pb = P2[(size_t)s*2 + 1];
    float y0 = w.x*pa.x + w.y*pa.z + w.z*pb.x + w.w*pb.z;
    float y1 = w.x*pa.y + w.y*pa.w + w.z*pb.y + w.w*pb.w;
    atomicAdd(out2 + (size_t)d*2 + 0, y0);
    atomicAdd(out2 + (size_t)d*2 + 1, y1);
    float4 qa = P2[(size_t)d*2], qb = P2[(size_t)d*2 + 1];
    float z0 = w.x*qa.x + w.y*qa.z + w.z*qb.x + w.w*qb.z;
    float z1 = w.x*qa.y + w.y*qa.w + w.z*qb.y + w.w*qb.w;
    atomicAdd(out2 + (size_t)s*2 + 0, z0);
    atomicAdd(out2 + (size_t)s*2 + 1, z1);
}

__global__ __launch_bounds__(256) void logsoftmax_k(
    const float* __restrict__ out2, float* __restrict__ out, int N)
{
    int n = blockIdx.x * 256 + threadIdx.x;
    if (n >= N) return;
    float o0 = out2[(size_t)n*2], o1 = out2[(size_t)n*2 + 1];
    float m = fmaxf(o0, o1);
    float lse = m + logf(expf(o0 - m) + expf(o1 - m));
    out[(size_t)n*2]     = o0 - lse;
    out[(size_t)n*2 + 1] = o1 - lse;
}

extern "C" void kernel_launch(void* const* d_in, const int* in_sizes, int n_in,
                              void* d_out, int out_size, void* d_ws, size_t ws_size,
                              hipStream_t stream)
{
    const float* x     = (const float*)d_in[0];
    const int*   ei    = (const int*)d_in[1];
    const float* attr  = (const float*)d_in[2];
    const float* cut   = (const float*)d_in[3];
    const float* cw1   = (const float*)d_in[4];
    const float* cb1   = (const float*)d_in[5];
    const float* f1w1  = (const float*)d_in[6];
    const float* f1b1  = (const float*)d_in[7];
    const float* f2w1  = (const float*)d_in[8];
    const float* f2b1  = (const float*)d_in[9];
    const float* th1   = (const float*)d_in[10];
    const float* rt1   = (const float*)d_in[11];
    const float* bs1   = (const float*)d_in[12];
    const float* cw2   = (const float*)d_in[13];
    const float* cb2   = (const float*)d_in[14];
    const float* f1w2  = (const float*)d_in[15];
    const float* f1b2  = (const float*)d_in[16];
    const float* f2w2  = (const float*)d_in[17];
    const float* f2b2  = (const float*)d_in[18];
    const float* th2   = (const float*)d_in[19];
    const float* rt2   = (const float*)d_in[20];
    const float* bs2   = (const float*)d_in[21];

    const int N = in_sizes[0] / 64;
    const int E = in_sizes[1] / 2;

    float* ws     = (float*)d_ws;
    float* wedge1 = ws;                              // 4E
    float* wedge2 = wedge1 + (size_t)E * 4;          // 4E
    __half* x_h   = (__half*)(wedge2 + (size_t)E*4); // N*64 halves = 32N floats (128B-aligned rows)
    float* h1     = (float*)(x_h + (size_t)N * 64);  // 20N
    float* o2     = h1     + (size_t)N * 20;         // 2N
    float* P2     = o2     + (size_t)N * 2;          // 8N
    int*   cnt    = (int*)(P2 + (size_t)N * 8);      // N
    unsigned* slots = (unsigned*)(cnt + N);          // N*CAP
    float* P1     = (float*)slots;                   // fallback only: 80N

    size_t base_floats = (size_t)8*E + 63*(size_t)N;
    int CAP = 0;
    if (ws_size / 4 > base_floats) {
        size_t cap_elems = (ws_size / 4 - base_floats) / (size_t)N;
        CAP = (int)(cap_elems > 128 ? 128 : cap_elems);
    }
    int doFill = (CAP >= 72) ? 1 : 0;

    if (doFill) {
        hipMemsetAsync(cnt, 0, (size_t)N * 4, stream);
        filter_fill_kernel<<<(E + 255) / 256, 256, 0, stream>>>(
            attr, cut, cw1, cb1, f1w1, f1b1, f2w1, f2b1,
            cw2, cb2, f1w2, f1b2, f2w2, f2b2,
            ei, cnt, slots, wedge1, wedge2, E, CAP, 1);
        node_prep1b<<<(N * 8 + 255) / 256, 256, 0, stream>>>(x, rt1, bs1, h1, x_h, N);
        gather1_fused<<<(N * 8 + 255) / 256, 256, 0, stream>>>(
            ei, cnt, slots, (const float4*)wedge1, x_h, h1,
            th1, rt2, th2, bs2, o2, P2, N, E, CAP);
        gather2_lsm_kernel<<<(N + 255) / 256, 256, 0, stream>>>(
            ei, cnt, slots, (const float4*)wedge2, (const float4*)P2, o2,
            (float*)d_out, N, E, CAP);
    } else {
        // Fallback: atomic scatter (correct but slow).
        filter_fill_kernel<<<(E + 255) / 256, 256, 0, stream>>>(
            attr, cut, cw1, cb1, f1w1, f1b1, f2w1, f2b1,
            cw2, cb2, f1w2, f1b2, f2w2, f2b2,
            ei, cnt, slots, wedge1, wedge2, E, 0, 0);
        node_prep1<<<(N + 7) / 8, 256, 0, stream>>>(x, rt1, th1, bs1, h1, P1, N);
        edge_scatter1<<<(E + 255) / 256, 256, 0, stream>>>(
            ei, (const float4*)wedge1, (const float4*)P1, h1, E);
        node_prep2<<<(N + 255) / 256, 256, 0, stream>>>(h1, rt2, th2, bs2, o2, P2, N);
        edge_scatter2<<<(E + 255) / 256, 256, 0, stream>>>(
            ei, (const float4*)wedge2, (const float4*)P2, o2, E);
        logsoftmax_k<<<(N + 255) / 256, 256, 0, stream>>>(o2, (float*)d_out, N);
    }
}

// Round 4
// 763.288 us; speedup vs baseline: 5.1609x; 1.2025x over previous
//
#include <hip/hip_runtime.h>
#include <hip/hip_fp16.h>
#include <math.h>

// Problem constants: F_IN=64, K=16, C=20, L=4, H1=20, H2=2
// N=100k nodes, E=1.6M undirected edges (3.2M directed after mirroring).
//
// Filter-net conv is evaluated analytically: conv input ch0 = a - cut[k] is
// affine in a; ch1 = [a > cut[k]] is a step function of idx = #{cut < a}.
// y[k] = b + S*a - T[k] + step(k,idx) -> max over k = max of 6 candidates
// using per-channel prefix/suffix minima of T (tables built once per block).

// ---------------- K1: filter nets (analytic conv) + incidence-list fill ---------
__global__ __launch_bounds__(256) void filter_fill_kernel(
    const float* __restrict__ attr, const float* __restrict__ cutoffs,
    const float* __restrict__ cw1, const float* __restrict__ cb1,
    const float* __restrict__ f1w1, const float* __restrict__ f1b1,
    const float* __restrict__ f2w1, const float* __restrict__ f2b1,
    const float* __restrict__ cw2, const float* __restrict__ cb2,
    const float* __restrict__ f1w2, const float* __restrict__ f1b2,
    const float* __restrict__ f2w2, const float* __restrict__ f2b2,
    const int* __restrict__ ei, int* __restrict__ cnt, unsigned* __restrict__ slots,
    float* __restrict__ wedge1, float* __restrict__ wedge2, int E, int CAP, int doFill)
{
    __shared__ float s_cut[16];
    __shared__ float s_w[2][344]; // cw(120) cb(20) f1w(160) f1b(8) f2w(32) f2b(4)
    __shared__ float tab[2 * 20 * 64];
    int tid = threadIdx.x;
    if (tid < 16) s_cut[tid] = cutoffs[tid];
    for (int i = tid; i < 344; i += 256) {
        float v1, v2;
        if (i < 120)      { v1 = cw1[i];       v2 = cw2[i]; }
        else if (i < 140) { v1 = cb1[i-120];   v2 = cb2[i-120]; }
        else if (i < 300) { v1 = f1w1[i-140];  v2 = f1w2[i-140]; }
        else if (i < 308) { v1 = f1b1[i-300];  v2 = f1b2[i-300]; }
        else if (i < 340) { v1 = f2w1[i-308];  v2 = f2w2[i-308]; }
        else              { v1 = f2b1[i-340];  v2 = f2b2[i-340]; }
        s_w[0][i] = v1; s_w[1][i] = v2;
    }
    __syncthreads();
    // Build per-(layer,channel) tables: one thread per pair.
    if (tid < 40) {
        int l = tid / 20, ch = tid % 20;
        const float* W = s_w[l];
        float w00 = W[ch*6+0], w01 = W[ch*6+1], w02 = W[ch*6+2];
        float w10 = W[ch*6+3], w11 = W[ch*6+4], w12 = W[ch*6+5];
        float b = W[120 + ch];
        float* tb = &tab[(l*20 + ch) * 64];
        // T[k]: weighted cutoff sums (conv "negative" part); zero padding at ends.
        tb[0]  = w01*s_cut[0]  + w02*s_cut[1];
        for (int k = 1; k <= 14; ++k)
            tb[k] = w00*s_cut[k-1] + w01*s_cut[k] + w02*s_cut[k+1];
        tb[15] = w00*s_cut[14] + w01*s_cut[15];
        // prefix min of T over interior [1..j]
        float pm = tb[1]; tb[16+1] = pm;
        for (int j = 2; j <= 14; ++j) { pm = fminf(pm, tb[j]); tb[16+j] = pm; }
        // suffix min of T over interior [j..14]
        float qm = tb[14]; tb[32+14] = qm;
        for (int j = 13; j >= 1; --j) { qm = fminf(qm, tb[j]); tb[32+j] = qm; }
        tb[48] = w00 + w01 + w02;  // S  (interior a-coef)
        tb[49] = w01 + w02;        // Sd0 (k=0 a-coef)
        tb[50] = w00 + w01;        // S15 (k=15 a-coef)
        tb[51] = w10 + w11 + w12;  // W3
        tb[52] = w10 + w11;        // W2
        tb[53] = w10;
        tb[54] = w11;
        tb[55] = w12;
        tb[56] = b;
    }
    __syncthreads();
    int e = blockIdx.x * 256 + tid;
    if (e >= E) return;

    // Incidence insert: slot value = directed edge id (de). nbr = ei[de].
    if (doFill) {
        int s = ei[e], d = ei[E + e];
        int p = atomicAdd(&cnt[d], 1);
        if (p < CAP) slots[(size_t)d * CAP + p] = (unsigned)e;        // incoming: nbr=src=ei[e]
        int p2 = atomicAdd(&cnt[s], 1);
        if (p2 < CAP) slots[(size_t)s * CAP + p2] = (unsigned)(e + E); // mirrored: nbr=dst=ei[E+e]
    }

    float a = attr[e];
    int idx = 0;
    #pragma unroll
    for (int k = 0; k < 16; ++k) idx += (a > s_cut[k]) ? 1 : 0;

    #pragma unroll
    for (int layer = 0; layer < 2; ++layer) {
        const float* W = s_w[layer];
        float h[20];
        #pragma unroll
        for (int c = 0; c < 20; ++c) {
            const float* tb = &tab[(layer*20 + c) * 64];
            float b = tb[56];
            float base = fmaf(tb[48], a, b);
            // k=0 candidate
            float y0 = fmaf(tb[49], a, b) - tb[0];
            y0 += (idx >= 1 ? tb[54] : 0.f) + (idx >= 2 ? tb[55] : 0.f);
            float m = y0;
            // k=15 candidate
            float y15 = fmaf(tb[50], a, b) - tb[15];
            y15 += (idx >= 15 ? tb[53] : 0.f) + (idx >= 16 ? tb[54] : 0.f);
            m = fmaxf(m, y15);
            // Band A: k in [1, idx-2], step = W3
            {
                int j = idx - 2; j = j > 14 ? 14 : j;
                float v = base + tb[51] - tb[16 + j];
                m = (idx >= 3) ? fmaxf(m, v) : m;
            }
            // Band B: k = idx-1 (interior), step = W2
            {
                float v = base + tb[52] - tb[(idx >= 2 && idx <= 15) ? (idx-1) : 1];
                m = (idx >= 2 && idx <= 15) ? fmaxf(m, v) : m;
            }
            // Band C: k = idx (interior), step = w10
            {
                float v = base + tb[53] - tb[(idx >= 1 && idx <= 14) ? idx : 1];
                m = (idx >= 1 && idx <= 14) ? fmaxf(m, v) : m;
            }
            // Band D: k in [idx+1, 14], step = 0
            {
                int j = idx + 1; j = j < 1 ? 1 : j;
                float v = base - tb[32 + (j > 14 ? 14 : j)];
                m = (idx <= 13) ? fmaxf(m, v) : m;
            }
            h[c] = fmaxf(m, 0.f);
        }
        float g[8];
        #pragma unroll
        for (int j = 0; j < 8; ++j) {
            float t = W[300 + j];
            #pragma unroll
            for (int c = 0; c < 20; ++c) t += W[140 + j*20 + c] * h[c];
            g[j] = fmaxf(t, 0.f);
        }
        float4 wo;
        float* wp = (float*)&wo;
        #pragma unroll
        for (int l = 0; l < 4; ++l) {
            float t = W[340 + l];
            #pragma unroll
            for (int j = 0; j < 8; ++j) t += W[308 + l*8 + j] * g[j];
            wp[l] = fmaxf(t, 0.f);
        }
        float4* dstp = (float4*)(layer == 0 ? wedge1 : wedge2);
        dstp[e] = wo;
    }
}

// ---------------- K2: h1 = x@root1+bias1 ; x_h = fp16(x) ------------------------
__global__ __launch_bounds__(256) void node_prep1b(
    const float* __restrict__ x, const float* __restrict__ root1,
    const float* __restrict__ bias1, float* __restrict__ h1,
    __half* __restrict__ x_h, int N)
{
    __shared__ float r1s[64 * 21];
    __shared__ float sb[20];
    int tid = threadIdx.x;
    for (int i = tid; i < 1280; i += 256) {
        int f = i / 20, h = i % 20;
        r1s[f*21 + h] = root1[i];
    }
    if (tid < 20) sb[tid] = bias1[tid];
    __syncthreads();
    int t = blockIdx.x * 256 + tid;
    int n = t >> 3, q = t & 7;
    if (n >= N) return;
    const float4* xr = (const float4*)(x + (size_t)n*64 + q*8);
    float4 va = xr[0], vb = xr[1];
    float xf[8] = {va.x, va.y, va.z, va.w, vb.x, vb.y, vb.z, vb.w};
    __half hh[8];
    #pragma unroll
    for (int j = 0; j < 8; ++j) hh[j] = __float2half(xf[j]);
    *(uint4*)(x_h + (size_t)n*64 + q*8) = *(const uint4*)hh;
    float p[20];
    #pragma unroll
    for (int h = 0; h < 20; ++h) p[h] = 0.f;
    #pragma unroll
    for (int j = 0; j < 8; ++j) {
        float xv = xf[j];
        int base = (q*8 + j) * 21;
        #pragma unroll
        for (int h = 0; h < 20; ++h) p[h] += xv * r1s[base + h];
    }
    #pragma unroll
    for (int m = 1; m < 8; m <<= 1) {
        #pragma unroll
        for (int h = 0; h < 20; ++h) p[h] += __shfl_xor(p[h], m, 64);
    }
    if (q < 5) {
        float4 o;
        o.x = p[q*4+0] + sb[q*4+0];
        o.y = p[q*4+1] + sb[q*4+1];
        o.z = p[q*4+2] + sb[q*4+2];
        o.w = p[q*4+3] + sb[q*4+3];
        *(float4*)(h1 + (size_t)n*20 + q*4) = o;
    }
}

// ---------------- K3: gather x_h, theta1-apply, fused node_prep2 ----------------
// 8 lanes per node; two edges per loop iteration (2x memory-level parallelism).
__global__ __launch_bounds__(256) void gather1_fused(
    const int* __restrict__ ei, const int* __restrict__ cnt,
    const unsigned* __restrict__ slots, const float4* __restrict__ wedge1,
    const __half* __restrict__ x_h, const float* __restrict__ h1,
    const float* __restrict__ theta1,
    const float* __restrict__ root2, const float* __restrict__ theta2,
    const float* __restrict__ bias2,
    float* __restrict__ o2, float* __restrict__ P2,
    int N, int E, int CAP)
{
    __shared__ float th[4 * 64 * 21];
    __shared__ float w2s[200];
    __shared__ float w2b[2];
    int tid = threadIdx.x;
    for (int i = tid; i < 5120; i += 256) {
        int l = i / 1280, f = (i / 20) % 64, h = i % 20;
        th[(l*64 + f)*21 + h] = theta1[i];
    }
    for (int i = tid; i < 200; i += 256) {
        int o = i / 20, h = i % 20;
        float v;
        if (o < 2) v = root2[h*2 + o];
        else { int l = (o-2) >> 1, jj = (o-2) & 1; v = theta2[l*40 + h*2 + jj]; }
        w2s[i] = v;
    }
    if (tid < 2) w2b[tid] = bias2[tid];
    __syncthreads();
    int t = blockIdx.x * 256 + tid;
    int n = t >> 3, q = t & 7;
    if (n >= N) return;
    int c = cnt[n]; if (c > CAP) c = CAP;
    const unsigned* sl = slots + (size_t)n * CAP;
    float acc[4][8];
    #pragma unroll
    for (int l = 0; l < 4; ++l)
        #pragma unroll
        for (int j = 0; j < 8; ++j) acc[l][j] = 0.f;
    int half = (c + 1) >> 1;
    for (int i = 0; i < half; ++i) {
        unsigned de1 = sl[i];
        int has2 = (i + half) < c;
        unsigned de2 = has2 ? sl[i + half] : de1;
        int nbr1 = ei[de1];
        int nbr2 = ei[de2];
        unsigned we1 = de1 < (unsigned)E ? de1 : de1 - (unsigned)E;
        unsigned we2 = de2 < (unsigned)E ? de2 : de2 - (unsigned)E;
        float4 w1 = wedge1[we1];
        float4 w2 = wedge1[we2];
        float z = has2 ? 1.f : 0.f;
        w2.x *= z; w2.y *= z; w2.z *= z; w2.w *= z;
        uint4 hx1 = *(const uint4*)(x_h + (size_t)nbr1*64 + q*8);
        uint4 hx2 = *(const uint4*)(x_h + (size_t)nbr2*64 + q*8);
        const __half* hp1 = (const __half*)&hx1;
        const __half* hp2 = (const __half*)&hx2;
        #pragma unroll
        for (int j2 = 0; j2 < 8; ++j2) {
            float xa = __half2float(hp1[j2]);
            float xb = __half2float(hp2[j2]);
            acc[0][j2] += w1.x * xa + w2.x * xb;
            acc[1][j2] += w1.y * xa + w2.y * xb;
            acc[2][j2] += w1.z * xa + w2.z * xb;
            acc[3][j2] += w1.w * xa + w2.w * xb;
        }
    }
    float p[20];
    #pragma unroll
    for (int h = 0; h < 20; ++h) p[h] = 0.f;
    #pragma unroll
    for (int l = 0; l < 4; ++l) {
        #pragma unroll
        for (int j2 = 0; j2 < 8; ++j2) {
            float a = acc[l][j2];
            int base = ((l << 6) + (q << 3) + j2) * 21;
            #pragma unroll
            for (int h = 0; h < 20; ++h) p[h] += a * th[base + h];
        }
    }
    #pragma unroll
    for (int m = 1; m < 8; m <<= 1) {
        #pragma unroll
        for (int h = 0; h < 20; ++h) p[h] += __shfl_xor(p[h], m, 64);
    }
    const float4* hb = (const float4*)(h1 + (size_t)n*20);
    float hv[20];
    #pragma unroll
    for (int qq = 0; qq < 5; ++qq) {
        float4 v = hb[qq];
        hv[qq*4+0] = fmaxf(p[qq*4+0] + v.x, 0.f);
        hv[qq*4+1] = fmaxf(p[qq*4+1] + v.y, 0.f);
        hv[qq*4+2] = fmaxf(p[qq*4+2] + v.z, 0.f);
        hv[qq*4+3] = fmaxf(p[qq*4+3] + v.w, 0.f);
    }
    for (int o = q; o < 10; o += 8) {
        float v = (o < 2) ? w2b[o] : 0.f;
        #pragma unroll
        for (int h = 0; h < 20; ++h) v += hv[h] * w2s[o*20 + h];
        if (o < 2) o2[(size_t)n*2 + o] = v;
        else       P2[(size_t)n*8 + (o - 2)] = v;
    }
}

// ---------------- K4: gather layer 2 (8 lanes/node) + fused log_softmax ---------
__global__ __launch_bounds__(256) void gather2_lsm_kernel(
    const int* __restrict__ ei, const int* __restrict__ cnt,
    const unsigned* __restrict__ slots, const float4* __restrict__ wedge2,
    const float4* __restrict__ P2, const float* __restrict__ o2,
    float* __restrict__ out, int N, int E, int CAP)
{
    int t = blockIdx.x * 256 + threadIdx.x;
    int n = t >> 3, r = t & 7;
    if (n >= N) return;
    int c = cnt[n]; if (c > CAP) c = CAP;
    const unsigned* sl = slots + (size_t)n * CAP;
    float o0 = 0.f, o1 = 0.f;
    for (int i = r; i < c; i += 8) {
        unsigned de = sl[i];
        int nbr = ei[de];
        unsigned we = de < (unsigned)E ? de : de - (unsigned)E;
        float4 w = wedge2[we];
        float4 pa = P2[(size_t)nbr*2], pb = P2[(size_t)nbr*2 + 1];
        o0 += w.x*pa.x + w.y*pa.z + w.z*pb.x + w.w*pb.z;
        o1 += w.x*pa.y + w.y*pa.w + w.z*pb.y + w.w*pb.w;
    }
    #pragma unroll
    for (int m = 1; m < 8; m <<= 1) {
        o0 += __shfl_xor(o0, m, 64);
        o1 += __shfl_xor(o1, m, 64);
    }
    if (r == 0) {
        o0 += o2[(size_t)n*2];
        o1 += o2[(size_t)n*2 + 1];
        float mx = fmaxf(o0, o1);
        float lse = mx + logf(expf(o0 - mx) + expf(o1 - mx));
        out[(size_t)n*2]     = o0 - lse;
        out[(size_t)n*2 + 1] = o1 - lse;
    }
}

// ================= Fallback path (atomic scatter) if workspace too small ========
__global__ __launch_bounds__(256) void node_prep1(
    const float* __restrict__ x, const float* __restrict__ root1,
    const float* __restrict__ theta1, const float* __restrict__ bias1,
    float* __restrict__ h1, float* __restrict__ P1, int N)
{
    __shared__ float Ws[64 * 100];
    __shared__ float xs[8 * 64];
    __shared__ float sb[20];
    int tid = threadIdx.x;
    for (int i = tid; i < 6400; i += 256) {
        int f = i / 100, c = i % 100;
        float v;
        if (c < 20) v = root1[f*20 + c];
        else { int l = (c-20)/20, hh = (c-20)%20; v = theta1[l*1280 + f*20 + hh]; }
        Ws[i] = v;
    }
    if (tid < 20) sb[tid] = bias1[tid];
    int nb = blockIdx.x * 8;
    for (int i = tid; i < 512; i += 256) {
        int nl = i >> 6, f = i & 63;
        int n = nb + nl;
        xs[i] = (n < N) ? x[(size_t)n*64 + f] : 0.f;
    }
    __syncthreads();
    for (int i = tid; i < 800; i += 256) {
        int nl = i / 100, c = i % 100;
        int n = nb + nl;
        if (n >= N) continue;
        float acc = 0.f;
        #pragma unroll 16
        for (int f = 0; f < 64; ++f) acc += xs[nl*64 + f] * Ws[f*100 + c];
        if (c < 20) h1[(size_t)n*20 + c] = acc + sb[c];
        else        P1[(size_t)n*80 + (c - 20)] = acc;
    }
}

__global__ __launch_bounds__(256) void edge_scatter1(
    const int* __restrict__ ei, const float4* __restrict__ wedge1,
    const float4* __restrict__ P1, float* __restrict__ h1, int E)
{
    int e = blockIdx.x * 256 + threadIdx.x;
    if (e >= E) return;
    int s = ei[e], d = ei[E + e];
    float4 w = wedge1[e];
    const float4* Ps = P1 + (size_t)s * 20;
    const float4* Pd = P1 + (size_t)d * 20;
    float* Hs = h1 + (size_t)s * 20;
    float* Hd = h1 + (size_t)d * 20;
    #pragma unroll
    for (int q = 0; q < 5; ++q) {
        float4 a0 = Ps[q], a1 = Ps[5+q], a2 = Ps[10+q], a3 = Ps[15+q];
        atomicAdd(Hd + q*4 + 0, w.x*a0.x + w.y*a1.x + w.z*a2.x + w.w*a3.x);
        atomicAdd(Hd + q*4 + 1, w.x*a0.y + w.y*a1.y + w.z*a2.y + w.w*a3.y);
        atomicAdd(Hd + q*4 + 2, w.x*a0.z + w.y*a1.z + w.z*a2.z + w.w*a3.z);
        atomicAdd(Hd + q*4 + 3, w.x*a0.w + w.y*a1.w + w.z*a2.w + w.w*a3.w);
        float4 b0 = Pd[q], b1 = Pd[5+q], b2 = Pd[10+q], b3 = Pd[15+q];
        atomicAdd(Hs + q*4 + 0, w.x*b0.x + w.y*b1.x + w.z*b2.x + w.w*b3.x);
        atomicAdd(Hs + q*4 + 1, w.x*b0.y + w.y*b1.y + w.z*b2.y + w.w*b3.y);
        atomicAdd(Hs + q*4 + 2, w.x*b0.z + w.y*b1.z + w.z*b2.z + w.w*b3.z);
        atomicAdd(Hs + q*4 + 3, w.x*b0.w + w.y*b1.w + w.z*b2.w + w.w*b3.w);
    }
}

__global__ __launch_bounds__(256) void node_prep2(
    const float* __restrict__ h1, const float* __restrict__ root2,
    const float* __restrict__ theta2, const float* __restrict__ bias2,
    float* __restrict__ out2, float* __restrict__ P2, int N)
{
    __shared__ float sr[40], st[160], sb2[2];
    int tid = threadIdx.x;
    if (tid < 40) sr[tid] = root2[tid];
    if (tid >= 64 && tid < 224) st[tid - 64] = theta2[tid - 64];
    if (tid < 2) sb2[tid] = bias2[tid];
    __syncthreads();
    int n = blockIdx.x * 256 + tid;
    if (n >= N) return;
    float hv[20];
    const float4* hp = (const float4*)(h1 + (size_t)n * 20);
    #pragma unroll
    for (int q = 0; q < 5; ++q) {
        float4 v = hp[q];
        hv[q*4+0] = fmaxf(v.x, 0.f);
        hv[q*4+1] = fmaxf(v.y, 0.f);
        hv[q*4+2] = fmaxf(v.z, 0.f);
        hv[q*4+3] = fmaxf(v.w, 0.f);
    }
    float o0 = sb2[0], o1 = sb2[1];
    #pragma unroll
    for (int h = 0; h < 20; ++h) { o0 += hv[h]*sr[h*2]; o1 += hv[h]*sr[h*2+1]; }
    out2[(size_t)n*2 + 0] = o0;
    out2[(size_t)n*2 + 1] = o1;
    #pragma unroll
    for (int l = 0; l < 4; ++l) {
        float p0 = 0.f, p1 = 0.f;
        #pragma unroll
        for (int h = 0; h < 20; ++h) {
            p0 += hv[h]*st[l*40 + h*2];
            p1 += hv[h]*st[l*40 + h*2 + 1];
        }
        P2[(size_t)n*8 + l*2 + 0] = p0;
        P2[(size_t)n*8 + l*2 + 1] = p1;
    }
}

__global__ __launch_bounds__(256) void edge_scatter2(
    const int* __restrict__ ei, const float4* __restrict__ wedge2,
    const float4* __restrict__ P2, float* __restrict__ out2, int E)
{
    int e = blockIdx.x * 256 + threadIdx.x;
    if (e >= E) return;
    int s = ei[e], d = ei[E + e];
    float4 w = wedge2[e];
    float4 pa = P2[(size_t)s*2], pb = P2[(size_t)s*2 + 1];
    float y0 = w.x*pa.x + w.y*pa.z + w.z*pb.x + w.w*pb.z;
    float y1 = w.x*pa.y + w.y*pa.w + w.z*pb.y + w.w*pb.w;
    atomicAdd(out2 + (size_t)d*2 + 0, y0);
    atomicAdd(out2 + (size_t)d*2 + 1, y1);
    float4 qa = P2[(size_t)d*2], qb = P2[(size_t)d*2 + 1];
    float z0 = w.x*qa.x + w.y*qa.z + w.z*qb.x + w.w*qb.z;
    float z1 = w.x*qa.y + w.y*qa.w + w.z*qb.y + w.w*qb.w;
    atomicAdd(out2 + (size_t)s*2 + 0, z0);
    atomicAdd(out2 + (size_t)s*2 + 1, z1);
}

__global__ __launch_bounds__(256) void logsoftmax_k(
    const float* __restrict__ out2, float* __restrict__ out, int N)
{
    int n = blockIdx.x * 256 + threadIdx.x;
    if (n >= N) return;
    float o0 = out2[(size_t)n*2], o1 = out2[(size_t)n*2 + 1];
    float m = fmaxf(o0, o1);
    float lse = m + logf(expf(o0 - m) + expf(o1 - m));
    out[(size_t)n*2]     = o0 - lse;
    out[(size_t)n*2 + 1] = o1 - lse;
}

extern "C" void kernel_launch(void* const* d_in, const int* in_sizes, int n_in,
                              void* d_out, int out_size, void* d_ws, size_t ws_size,
                              hipStream_t stream)
{
    const float* x     = (const float*)d_in[0];
    const int*   ei    = (const int*)d_in[1];
    const float* attr  = (const float*)d_in[2];
    const float* cut   = (const float*)d_in[3];
    const float* cw1   = (const float*)d_in[4];
    const float* cb1   = (const float*)d_in[5];
    const float* f1w1  = (const float*)d_in[6];
    const float* f1b1  = (const float*)d_in[7];
    const float* f2w1  = (const float*)d_in[8];
    const float* f2b1  = (const float*)d_in[9];
    const float* th1   = (const float*)d_in[10];
    const float* rt1   = (const float*)d_in[11];
    const float* bs1   = (const float*)d_in[12];
    const float* cw2   = (const float*)d_in[13];
    const float* cb2   = (const float*)d_in[14];
    const float* f1w2  = (const float*)d_in[15];
    const float* f1b2  = (const float*)d_in[16];
    const float* f2w2  = (const float*)d_in[17];
    const float* f2b2  = (const float*)d_in[18];
    const float* th2   = (const float*)d_in[19];
    const float* rt2   = (const float*)d_in[20];
    const float* bs2   = (const float*)d_in[21];

    const int N = in_sizes[0] / 64;
    const int E = in_sizes[1] / 2;

    float* ws     = (float*)d_ws;
    float* wedge1 = ws;                              // 4E
    float* wedge2 = wedge1 + (size_t)E * 4;          // 4E
    __half* x_h   = (__half*)(wedge2 + (size_t)E*4); // 32N floats (128B-aligned rows)
    float* h1     = (float*)(x_h + (size_t)N * 64);  // 20N
    float* o2     = h1     + (size_t)N * 20;         // 2N
    float* P2     = o2     + (size_t)N * 2;          // 8N
    int*   cnt    = (int*)(P2 + (size_t)N * 8);      // N
    unsigned* slots = (unsigned*)(cnt + N);          // N*CAP
    float* P1     = (float*)slots;                   // fallback only: 80N

    size_t base_floats = (size_t)8*E + 63*(size_t)N;
    int CAP = 0;
    if (ws_size / 4 > base_floats) {
        size_t cap_elems = (ws_size / 4 - base_floats) / (size_t)N;
        CAP = (int)(cap_elems > 128 ? 128 : cap_elems);
    }
    int doFill = (CAP >= 72) ? 1 : 0;

    if (doFill) {
        hipMemsetAsync(cnt, 0, (size_t)N * 4, stream);
        filter_fill_kernel<<<(E + 255) / 256, 256, 0, stream>>>(
            attr, cut, cw1, cb1, f1w1, f1b1, f2w1, f2b1,
            cw2, cb2, f1w2, f1b2, f2w2, f2b2,
            ei, cnt, slots, wedge1, wedge2, E, CAP, 1);
        node_prep1b<<<(N * 8 + 255) / 256, 256, 0, stream>>>(x, rt1, bs1, h1, x_h, N);
        gather1_fused<<<(N * 8 + 255) / 256, 256, 0, stream>>>(
            ei, cnt, slots, (const float4*)wedge1, x_h, h1,
            th1, rt2, th2, bs2, o2, P2, N, E, CAP);
        gather2_lsm_kernel<<<(N * 8 + 255) / 256, 256, 0, stream>>>(
            ei, cnt, slots, (const float4*)wedge2, (const float4*)P2, o2,
            (float*)d_out, N, E, CAP);
    } else {
        // Fallback: atomic scatter (correct but slow).
        filter_fill_kernel<<<(E + 255) / 256, 256, 0, stream>>>(
            attr, cut, cw1, cb1, f1w1, f1b1, f2w1, f2b1,
            cw2, cb2, f1w2, f1b2, f2w2, f2b2,
            ei, cnt, slots, wedge1, wedge2, E, 0, 0);
        node_prep1<<<(N + 7) / 8, 256, 0, stream>>>(x, rt1, th1, bs1, h1, P1, N);
        edge_scatter1<<<(E + 255) / 256, 256, 0, stream>>>(
            ei, (const float4*)wedge1, (const float4*)P1, h1, E);
        node_prep2<<<(N + 255) / 256, 256, 0, stream>>>(h1, rt2, th2, bs2, o2, P2, N);
        edge_scatter2<<<(E + 255) / 256, 256, 0, stream>>>(
            ei, (const float4*)wedge2, (const float4*)P2, o2, E);
        logsoftmax_k<<<(N + 255) / 256, 256, 0, stream>>>(o2, (float*)d_out, N);
    }
}